// Round 16
// baseline (47.764 us; speedup 1.0000x reference)
//
#include <hip/hip_runtime.h>
#include <math.h>

#define NPTS 4096
#define NB 4
#define EPSF 1e-6f

// ============================================================================
// gravity_align + t_center (exact reference arithmetic; bit-exact R1-R15).
// ============================================================================
__device__ __forceinline__ void gravity_align_rt(
    const float* __restrict__ g_p, const float* __restrict__ g_q,
    const float* sums, int b, float* R_out, float* t_out) {
    float gpx = g_p[3 * b + 0], gpy = g_p[3 * b + 1], gpz = g_p[3 * b + 2];
    float gqx = g_q[3 * b + 0], gqy = g_q[3 * b + 1], gqz = g_q[3 * b + 2];
    float nu = sqrtf(gpx * gpx + gpy * gpy + gpz * gpz);
    float du = fmaxf(nu, EPSF);
    float ux = gpx / du, uy = gpy / du, uz = gpz / du;
    float nv = sqrtf(gqx * gqx + gqy * gqy + gqz * gqz);
    float dv = fmaxf(nv, EPSF);
    float vx = gqx / dv, vy = gqy / dv, vz = gqz / dv;

    float ax = uy * vz - uz * vy;
    float ay = uz * vx - ux * vz;
    float az = ux * vy - uy * vx;
    float an = sqrtf(ax * ax + ay * ay + az * az);
    float dot = ux * vx + uy * vy + uz * vz;
    dot = fminf(1.0f, fmaxf(-1.0f, dot));
    bool parallel = (an < 1e-6f);

    float kx = ax / (an + EPSF), ky = ay / (an + EPSF), kz = az / (an + EPSF);
    float theta = acosf(dot);
    float st = sinf(theta), ct = cosf(theta);

    float K[9] = {0.f, -kz, ky,  kz, 0.f, -kx,  -ky, kx, 0.f};
    float KK[9];
    for (int i = 0; i < 3; ++i)
        for (int j = 0; j < 3; ++j) {
            float s2 = 0.f;
            for (int l = 0; l < 3; ++l) s2 += K[i * 3 + l] * K[l * 3 + j];
            KK[i * 3 + j] = s2;
        }
    float R[9];
    for (int i = 0; i < 9; ++i) {
        float I = (i == 0 || i == 4 || i == 8) ? 1.f : 0.f;
        R[i] = I + st * K[i] + (1.f - ct) * KK[i];
    }
    if (parallel) {
        if (dot < 0.f) {
            float bx, by, bz;
            if (fabsf(ux) < 0.9f) { bx = 1.f; by = 0.f; bz = 0.f; }
            else                  { bx = 0.f; by = 1.f; bz = 0.f; }
            float cx = uy * bz - uz * by;
            float cy = uz * bx - ux * bz;
            float cz = ux * by - uy * bx;
            float cn = sqrtf(cx * cx + cy * cy + cz * cz);
            float cd = fmaxf(cn, EPSF);
            cx /= cd; cy /= cd; cz /= cd;
            float K2[9] = {0.f, -cz, cy,  cz, 0.f, -cx,  -cy, cx, 0.f};
            float K2K2[9];
            for (int i = 0; i < 3; ++i)
                for (int j = 0; j < 3; ++j) {
                    float s2 = 0.f;
                    for (int l = 0; l < 3; ++l) s2 += K2[i * 3 + l] * K2[l * 3 + j];
                    K2K2[i * 3 + j] = s2;
                }
            for (int i = 0; i < 9; ++i) {
                float I = (i == 0 || i == 4 || i == 8) ? 1.f : 0.f;
                R[i] = I + 2.f * K2K2[i];
            }
        } else if (dot > 0.f) {
            for (int i = 0; i < 9; ++i) R[i] = (i == 0 || i == 4 || i == 8) ? 1.f : 0.f;
        }
    }
    float ms0 = sums[0] / (float)NPTS, ms1 = sums[1] / (float)NPTS, ms2 = sums[2] / (float)NPTS;
    float mt0 = sums[3] / (float)NPTS, mt1 = sums[4] / (float)NPTS, mt2 = sums[5] / (float)NPTS;
    for (int i = 0; i < 9; ++i) R_out[i] = R[i];
    t_out[0] = mt0 - (R[0] * ms0 + R[1] * ms1 + R[2] * ms2);
    t_out[1] = mt1 - (R[3] * ms0 + R[4] * ms1 + R[5] * ms2);
    t_out[2] = mt2 - (R[6] * ms0 + R[7] * ms1 + R[8] * ms2);
}

// ============================================================================
// K0a: per-batch means + R/t -> global Rt (verbatim, proven). Grid NB x 256.
// ============================================================================
__global__ void k0a_rt(const float* __restrict__ src, const float* __restrict__ tgt,
                       const float* __restrict__ g_p, const float* __restrict__ g_q,
                       float* __restrict__ Rt) {
    const int b = blockIdx.x;
    const int tid = threadIdx.x;
    const float* S = src + (size_t)b * 3 * NPTS;
    const float* T = tgt + (size_t)b * 3 * NPTS;

    float acc[6] = {0.f, 0.f, 0.f, 0.f, 0.f, 0.f};
    for (int n = tid; n < NPTS; n += 256) {
        acc[0] += S[n]; acc[1] += S[NPTS + n]; acc[2] += S[2 * NPTS + n];
        acc[3] += T[n]; acc[4] += T[NPTS + n]; acc[5] += T[2 * NPTS + n];
    }
    __shared__ float red[256];
    __shared__ float sums[6];
    for (int c = 0; c < 6; ++c) {
        red[tid] = acc[c];
        __syncthreads();
        for (int s = 128; s > 0; s >>= 1) {
            if (tid < s) red[tid] += red[tid + s];
            __syncthreads();
        }
        if (tid == 0) sums[c] = red[0];
        __syncthreads();
    }
    if (tid == 0) {
        float Rg[9], tc[3];
        gravity_align_rt(g_p, g_q, sums, b, Rg, tc);
        for (int i = 0; i < 9; ++i) Rt[b * 16 + i] = Rg[i];
        Rt[b * 16 + 9]  = tc[0];
        Rt[b * 16 + 10] = tc[1];
        Rt[b * 16 + 11] = tc[2];
    }
}

// ============================================================================
// kA: NN scan, V=4 own-points per lane x quarter-m candidates.
// Grid (16, NB, 8): zz = z*4 + q. 512 blocks x 1024 thr, 32KB LDS ->
// 2 blocks/CU, 32 waves/CU (the LDS/VALU-balanced point per R15 model:
// LDS 10.2us = VALU 10.2us per CU). Each lane owns n0,+64,+128,+192 (4
// independent best-chains, one broadcast ds_read feeds 4 evals); block
// scans quarter q's 1024 candidates staged from raw (proven exprs).
// Per-point order: 16 stripes x 64 ascending, strict >, stripe combine
// (proven). Cross-quarter combine happens in kB (ascending q, strict >,
// the R13-proven half-combine rule).
// ============================================================================
__global__ __launch_bounds__(1024, 8) void kA(
    const float* __restrict__ src, const float* __restrict__ tgt,
    const float* __restrict__ Rt,
    float* __restrict__ bestv, int* __restrict__ bidx,
    float* __restrict__ pw) {
    const int x = blockIdx.x;
    const int b = blockIdx.y;
    const int zz = blockIdx.z;
    const int z = zz >> 2;
    const int q = zz & 3;
    const int tid = threadIdx.x;
    const float* S = src + (size_t)b * 3 * NPTS;
    const float* T = tgt + (size_t)b * 3 * NPTS;
    const float R0 = Rt[b*16+0], R1 = Rt[b*16+1], R2 = Rt[b*16+2];
    const float R3 = Rt[b*16+3], R4 = Rt[b*16+4], R5 = Rt[b*16+5];
    const float R6 = Rt[b*16+6], R7 = Rt[b*16+7], R8 = Rt[b*16+8];
    const float t0 = Rt[b*16+9], t1 = Rt[b*16+10], t2 = Rt[b*16+11];

    __shared__ float4 buf[2048];          // 32 KB: stage (16KB) + combine alias
    float4* stage4 = buf;                 // first 1024 float4s
    const int mbase = q * 1024;

    const int nl = tid & 63;
    const int stripe = tid >> 6;          // 0..15, each scans 64 candidates
    const int n0 = x * 256 + nl;          // own points: n0 + 64*k, k=0..3
    float4 p[4];

    if (z == 0) {
        // stage = q-points from raw tgt (verbatim proven exprs)
        if (tid < 1024) {
            const int gi = mbase + tid;
            float q0 = T[gi], q1 = T[NPTS + gi], q2 = T[2 * NPTS + gi];
            float w = (q0 * q0 + q1 * q1 + q2 * q2) * -0.5f;
            stage4[tid] = make_float4(q0, q1, q2, w);
        }
        #pragma unroll
        for (int k = 0; k < 4; ++k) {
            const int n = n0 + 64 * k;
            float s0 = S[n], s1 = S[NPTS + n], s2 = S[2 * NPTS + n];
            float p0 = R0 * s0 + R1 * s1 + R2 * s2 + t0;
            float p1 = R3 * s0 + R4 * s1 + R5 * s2 + t1;
            float p2 = R6 * s0 + R7 * s1 + R8 * s2 + t2;
            p[k] = make_float4(p0, p1, p2, p0 * p0 + p1 * p1 + p2 * p2);
        }
    } else {
        // stage = p-points (R-transformed src, verbatim proven exprs)
        if (tid < 1024) {
            const int gi = mbase + tid;
            float s0 = S[gi], s1 = S[NPTS + gi], s2 = S[2 * NPTS + gi];
            float p0 = R0 * s0 + R1 * s1 + R2 * s2 + t0;
            float p1 = R3 * s0 + R4 * s1 + R5 * s2 + t1;
            float p2 = R6 * s0 + R7 * s1 + R8 * s2 + t2;
            float w = (p0 * p0 + p1 * p1 + p2 * p2) * -0.5f;
            stage4[tid] = make_float4(p0, p1, p2, w);
        }
        #pragma unroll
        for (int k = 0; k < 4; ++k) {
            const int n = n0 + 64 * k;
            float q0 = T[n], q1 = T[NPTS + n], q2 = T[2 * NPTS + n];
            p[k] = make_float4(q0, q1, q2, q0 * q0 + q1 * q1 + q2 * q2);
        }
    }
    __syncthreads();

    const int m0 = stripe << 6;           // local m in [0,1024)
    float best[4] = {-3.4e38f, -3.4e38f, -3.4e38f, -3.4e38f};
    int bi[4] = {m0, m0, m0, m0};
    #pragma unroll 8
    for (int m = m0; m < m0 + 64; ++m) {
        float4 qq = stage4[m];
        #pragma unroll
        for (int k = 0; k < 4; ++k) {
            float s = fmaf(p[k].x, qq.x, fmaf(p[k].y, qq.y, fmaf(p[k].z, qq.z, qq.w)));
            if (s > best[k]) { best[k] = s; bi[k] = m; }
        }
    }
    __syncthreads();

    // combine alias: 4x1024 floats (16KB) + 4x1024 ints (16KB) = 32KB
    float* combd = (float*)buf;
    int* combi = (int*)((float*)buf + 4096);
    #pragma unroll
    for (int k = 0; k < 4; ++k) {
        combd[k * 1024 + tid] = best[k];
        combi[k * 1024 + tid] = bi[k];
    }
    __syncthreads();
    if (stripe == 0) {
        #pragma unroll
        for (int k = 0; k < 4; ++k) {
            float bk = best[k];
            int ik = bi[k];
            for (int s2 = 1; s2 < 16; ++s2) {
                float d2 = combd[k * 1024 + s2 * 64 + nl];
                int i2 = combi[k * 1024 + s2 * 64 + nl];
                if (d2 > bk) { bk = d2; ik = i2; }   // ties: lower stripe wins
            }
            const size_t off = (size_t)(z * NB + b) * NPTS;
            const int n = n0 + 64 * k;
            bestv[(size_t)q * (2 * NB * NPTS) + off + n] = bk;
            bidx[(size_t)q * (2 * NB * NPTS) + off + n] = mbase + ik;
            if (q == 0) pw[off + n] = p[k].w;
        }
    }
}

// ============================================================================
// kB: 4-way quarter combine -> nn, redundant radix median + weights.
// Grid (64, NB, 2) x 1024. Quarter combine: strict >, ascending q
// (R13-proven rule: value = order-independent max; index = global
// first-occurrence). nn expr byte-identical to proven. Median = R9-proven
// radix select. Weights = R11-proven Rt-based arithmetic.
// ============================================================================
__global__ __launch_bounds__(1024, 8) void kB(
    const float* __restrict__ bestv, const int* __restrict__ bidx,
    const float* __restrict__ pw,
    const float* __restrict__ src_n, const float* __restrict__ tgt_n,
    const float* __restrict__ Rt,
    const float* __restrict__ g_q, const float* __restrict__ k_p,
    const float* __restrict__ k_q, float* __restrict__ out) {
    const int x = blockIdx.x;
    const int b = blockIdx.y;
    const int z = blockIdx.z;
    const int tid = threadIdx.x;
    const int wid = tid >> 6;
    const int lane = tid & 63;
    const size_t off = (size_t)(z * NB + b) * NPTS;
    const size_t QS = (size_t)2 * NB * NPTS;

    // ---- 4-way combine -> nn values (4 own points/thread for radix) ----
    unsigned int v[4];
    #pragma unroll
    for (int j = 0; j < 4; ++j) {
        const int n = tid + j * 1024;
        float sb = bestv[off + n];                 // q = 0
        #pragma unroll
        for (int qq = 1; qq < 4; ++qq) {
            float sq = bestv[(size_t)qq * QS + off + n];
            if (sq > sb) sb = sq;                  // strict: lower q wins ties
        }
        float d = fmaf(-2.0f, sb, pw[off + n]);
        float nv = sqrtf(fmaxf(d, 0.f) + EPSF);
        v[j] = __float_as_uint(nv);                // positive: uint order == float order
    }

    __shared__ int hist[16][256];
    __shared__ int tot[256];
    __shared__ int digit_s, base_s;

    const int shifts[4]   = {23, 15, 7, 0};
    const unsigned him[4] = {0x00000000u, 0x7F800000u, 0x7FFF8000u, 0x7FFFFF80u};
    const unsigned dm[4]  = {0xFFu, 0xFFu, 0xFFu, 0x7Fu};

    unsigned int prefix = 0u;
    int rank = 2047;

    for (int p = 0; p < 4; ++p) {
        const int sh = shifts[p];
        const unsigned himask = him[p];
        const unsigned dmask = dm[p];

        for (int k2 = lane; k2 < 256; k2 += 64) hist[wid][k2] = 0;
        __syncthreads();

        #pragma unroll
        for (int j = 0; j < 4; ++j) {
            if ((v[j] & himask) == prefix)
                atomicAdd(&hist[wid][(v[j] >> sh) & dmask], 1);
        }
        __syncthreads();

        if (tid < 256) {
            int t = 0;
            #pragma unroll
            for (int w = 0; w < 16; ++w) t += hist[w][tid];
            tot[tid] = t;
        }
        __syncthreads();

        if (wid == 0) {
            int c0 = tot[4 * lane + 0], c1 = tot[4 * lane + 1];
            int c2 = tot[4 * lane + 2], c3 = tot[4 * lane + 3];
            int s = c0 + c1 + c2 + c3;
            int incl = s;
            #pragma unroll
            for (int o = 1; o < 64; o <<= 1) {
                int t = __shfl_up(incl, o, 64);
                if (lane >= o) incl += t;
            }
            int base = incl - s;
            int cs[4] = {c0, c1, c2, c3};
            #pragma unroll
            for (int k2 = 0; k2 < 4; ++k2) {
                if (cs[k2] > 0 && rank >= base && rank < base + cs[k2]) {
                    digit_s = 4 * lane + k2;   // unique writer
                    base_s = base;
                }
                base += cs[k2];
            }
        }
        __syncthreads();
        prefix |= ((unsigned)digit_s) << sh;
        rank -= base_s;
        __syncthreads();
    }
    const float tauv = 3.0f * __uint_as_float(prefix);

    // ---- weights for this block's 64 own points (R11-proven Rt path) ----
    if (tid < 64) {
        const int n = x * 64 + tid;
        float sb = bestv[off + n];
        int jj = bidx[off + n];
        #pragma unroll
        for (int qq = 1; qq < 4; ++qq) {
            float sq = bestv[(size_t)qq * QS + off + n];
            if (sq > sb) { sb = sq; jj = bidx[(size_t)qq * QS + off + n]; }
        }
        float d = fmaf(-2.0f, sb, pw[off + n]);
        float nv = sqrtf(fmaxf(d, 0.f) + EPSF);

        const float* SN = src_n + (size_t)b * 3 * NPTS;
        const float* TN = tgt_n + (size_t)b * 3 * NPTS;
        const float R0 = Rt[b*16+0], R1 = Rt[b*16+1], R2 = Rt[b*16+2];
        const float R3 = Rt[b*16+3], R4 = Rt[b*16+4], R5 = Rt[b*16+5];
        const float R6 = Rt[b*16+6], R7 = Rt[b*16+7], R8 = Rt[b*16+8];
        const float gx = g_q[3 * b + 0], gy = g_q[3 * b + 1], gz = g_q[3 * b + 2];
        const float kp = k_p[b], kq = k_q[b];
        const float keff = kp * kq / (kp + kq + EPSF);

        float w;
        if (z == 0) {
            float a0 = SN[n], a1 = SN[NPTS + n], a2 = SN[2 * NPTS + n];
            float snx = R0 * a0 + R1 * a1 + R2 * a2;
            float sny = R3 * a0 + R4 * a1 + R5 * a2;
            float snz = R6 * a0 + R7 * a1 + R8 * a2;
            float inc = snx * gx + sny * gy + snz * gz;
            float tnx = TN[jj], tny = TN[NPTS + jj], tnz = TN[2 * NPTS + jj];
            float incr = tnx * gx + tny * gy + tnz * gz;
            float diff = inc - incr;
            float arg = 9.0f - keff * diff * diff;
            float sig = 1.f / (1.f + expf(-arg));
            float geom = (nv <= tauv) ? 1.f : 0.f;
            w = sig * geom;
        } else {
            float tnx = TN[n], tny = TN[NPTS + n], tnz = TN[2 * NPTS + n];
            float inc = tnx * gx + tny * gy + tnz * gz;
            float a0 = SN[jj], a1 = SN[NPTS + jj], a2 = SN[2 * NPTS + jj];
            float snx = R0 * a0 + R1 * a1 + R2 * a2;
            float sny = R3 * a0 + R4 * a1 + R5 * a2;
            float snz = R6 * a0 + R7 * a1 + R8 * a2;
            float incr = snx * gx + sny * gy + snz * gz;
            float diff = inc - incr;
            float arg = 9.0f - keff * diff * diff;
            float sig = 1.f / (1.f + expf(-arg));
            float geom = (nv <= tauv) ? 1.f : 0.f;
            w = sig * geom;
        }
        out[z * (NB * NPTS) + b * NPTS + n] = w;
    }
}

extern "C" void kernel_launch(void* const* d_in, const int* in_sizes, int n_in,
                              void* d_out, int out_size, void* d_ws, size_t ws_size,
                              hipStream_t stream) {
    const float* src   = (const float*)d_in[0];
    const float* tgt   = (const float*)d_in[1];
    const float* src_n = (const float*)d_in[2];
    const float* tgt_n = (const float*)d_in[3];
    const float* g_p   = (const float*)d_in[4];
    const float* k_p   = (const float*)d_in[5];
    const float* g_q   = (const float*)d_in[6];
    const float* k_q   = (const float*)d_in[7];
    float* out = (float*)d_out;

    const size_t QS = (size_t)2 * NB * NPTS;   // per-quarter plane (both z)
    float* bestv = (float*)d_ws;               // 4 * QS floats
    int* bidx = (int*)(bestv + 4 * QS);        // 4 * QS ints
    float* pw = (float*)(bidx + 4 * QS);       // QS floats
    float* Rt = pw + QS;                       // NB*16 floats

    k0a_rt<<<dim3(NB), dim3(256), 0, stream>>>(src, tgt, g_p, g_q, Rt);
    kA<<<dim3(16, NB, 8), dim3(1024), 0, stream>>>(src, tgt, Rt, bestv, bidx, pw);
    kB<<<dim3(NPTS / 64, NB, 2), dim3(1024), 0, stream>>>(bestv, bidx, pw,
                                                          src_n, tgt_n, Rt,
                                                          g_q, k_p, k_q, out);
}

// Round 17
// 46.511 us; speedup vs baseline: 1.0269x; 1.0269x over previous
//
#include <hip/hip_runtime.h>
#include <math.h>

#define NPTS 4096
#define NB 4
#define EPSF 1e-6f

// ============================================================================
// FINAL (reverted to R11 best-proven: 46.55us, absmax 0.0).
// Session ladder: 104.7 (R1) -> 78.7 (rank-count median) -> 61.5 (score-form
// scan + 512-thr) -> 53.3 (digit-radix median) -> 46.6 (stage-from-raw scan,
// redundant-median kcr). Scan variants V=1/V=2/V=4/split-m/scalar-path all
// plateau the total at 46.6-48.5 (R12-R16): combined LDS-broadcast-pipe +
// ~15-ops/pair VALU floor.
// ============================================================================

__device__ __forceinline__ void gravity_align_rt(
    const float* __restrict__ g_p, const float* __restrict__ g_q,
    const float* sums, int b, float* R_out, float* t_out) {
    float gpx = g_p[3 * b + 0], gpy = g_p[3 * b + 1], gpz = g_p[3 * b + 2];
    float gqx = g_q[3 * b + 0], gqy = g_q[3 * b + 1], gqz = g_q[3 * b + 2];
    float nu = sqrtf(gpx * gpx + gpy * gpy + gpz * gpz);
    float du = fmaxf(nu, EPSF);
    float ux = gpx / du, uy = gpy / du, uz = gpz / du;
    float nv = sqrtf(gqx * gqx + gqy * gqy + gqz * gqz);
    float dv = fmaxf(nv, EPSF);
    float vx = gqx / dv, vy = gqy / dv, vz = gqz / dv;

    float ax = uy * vz - uz * vy;
    float ay = uz * vx - ux * vz;
    float az = ux * vy - uy * vx;
    float an = sqrtf(ax * ax + ay * ay + az * az);
    float dot = ux * vx + uy * vy + uz * vz;
    dot = fminf(1.0f, fmaxf(-1.0f, dot));
    bool parallel = (an < 1e-6f);

    float kx = ax / (an + EPSF), ky = ay / (an + EPSF), kz = az / (an + EPSF);
    float theta = acosf(dot);
    float st = sinf(theta), ct = cosf(theta);

    float K[9] = {0.f, -kz, ky,  kz, 0.f, -kx,  -ky, kx, 0.f};
    float KK[9];
    for (int i = 0; i < 3; ++i)
        for (int j = 0; j < 3; ++j) {
            float s2 = 0.f;
            for (int l = 0; l < 3; ++l) s2 += K[i * 3 + l] * K[l * 3 + j];
            KK[i * 3 + j] = s2;
        }
    float R[9];
    for (int i = 0; i < 9; ++i) {
        float I = (i == 0 || i == 4 || i == 8) ? 1.f : 0.f;
        R[i] = I + st * K[i] + (1.f - ct) * KK[i];
    }
    if (parallel) {
        if (dot < 0.f) {
            float bx, by, bz;
            if (fabsf(ux) < 0.9f) { bx = 1.f; by = 0.f; bz = 0.f; }
            else                  { bx = 0.f; by = 1.f; bz = 0.f; }
            float cx = uy * bz - uz * by;
            float cy = uz * bx - ux * bz;
            float cz = ux * by - uy * bx;
            float cn = sqrtf(cx * cx + cy * cy + cz * cz);
            float cd = fmaxf(cn, EPSF);
            cx /= cd; cy /= cd; cz /= cd;
            float K2[9] = {0.f, -cz, cy,  cz, 0.f, -cx,  -cy, cx, 0.f};
            float K2K2[9];
            for (int i = 0; i < 3; ++i)
                for (int j = 0; j < 3; ++j) {
                    float s2 = 0.f;
                    for (int l = 0; l < 3; ++l) s2 += K2[i * 3 + l] * K2[l * 3 + j];
                    K2K2[i * 3 + j] = s2;
                }
            for (int i = 0; i < 9; ++i) {
                float I = (i == 0 || i == 4 || i == 8) ? 1.f : 0.f;
                R[i] = I + 2.f * K2K2[i];
            }
        } else if (dot > 0.f) {
            for (int i = 0; i < 9; ++i) R[i] = (i == 0 || i == 4 || i == 8) ? 1.f : 0.f;
        }
    }
    float ms0 = sums[0] / (float)NPTS, ms1 = sums[1] / (float)NPTS, ms2 = sums[2] / (float)NPTS;
    float mt0 = sums[3] / (float)NPTS, mt1 = sums[4] / (float)NPTS, mt2 = sums[5] / (float)NPTS;
    for (int i = 0; i < 9; ++i) R_out[i] = R[i];
    t_out[0] = mt0 - (R[0] * ms0 + R[1] * ms1 + R[2] * ms2);
    t_out[1] = mt1 - (R[3] * ms0 + R[4] * ms1 + R[5] * ms2);
    t_out[2] = mt2 - (R[6] * ms0 + R[7] * ms1 + R[8] * ms2);
}

// ============================================================================
// K0a: per-batch means + R/t -> global Rt. Grid NB x 256.
// ============================================================================
__global__ void k0a_rt(const float* __restrict__ src, const float* __restrict__ tgt,
                       const float* __restrict__ g_p, const float* __restrict__ g_q,
                       float* __restrict__ Rt) {
    const int b = blockIdx.x;
    const int tid = threadIdx.x;
    const float* S = src + (size_t)b * 3 * NPTS;
    const float* T = tgt + (size_t)b * 3 * NPTS;

    float acc[6] = {0.f, 0.f, 0.f, 0.f, 0.f, 0.f};
    for (int n = tid; n < NPTS; n += 256) {
        acc[0] += S[n]; acc[1] += S[NPTS + n]; acc[2] += S[2 * NPTS + n];
        acc[3] += T[n]; acc[4] += T[NPTS + n]; acc[5] += T[2 * NPTS + n];
    }
    __shared__ float red[256];
    __shared__ float sums[6];
    for (int c = 0; c < 6; ++c) {
        red[tid] = acc[c];
        __syncthreads();
        for (int s = 128; s > 0; s >>= 1) {
            if (tid < s) red[tid] += red[tid + s];
            __syncthreads();
        }
        if (tid == 0) sums[c] = red[0];
        __syncthreads();
    }
    if (tid == 0) {
        float Rg[9], tc[3];
        gravity_align_rt(g_p, g_q, sums, b, Rg, tc);
        for (int i = 0; i < 9; ++i) Rt[b * 16 + i] = Rg[i];
        Rt[b * 16 + 9]  = tc[0];
        Rt[b * 16 + 10] = tc[1];
        Rt[b * 16 + 11] = tc[2];
    }
}

// ============================================================================
// K1r: NN both directions, staging FROM RAW inputs + Rt. Grid (64, NB, 2)
// x 1024, 64KB LDS, 2 blocks/CU. 16 stripes x 256 ascending, strict >,
// stripe-order combine -> first-occurrence argmin bit-exact.
// ============================================================================
__global__ void k1r(const float* __restrict__ src, const float* __restrict__ tgt,
                    const float* __restrict__ Rt,
                    float* __restrict__ nnp, int* __restrict__ idxp,
                    float* __restrict__ nnq, int* __restrict__ idxq) {
    const int b = blockIdx.y;
    const int z = blockIdx.z;
    const int tid = threadIdx.x;
    const float* S = src + (size_t)b * 3 * NPTS;
    const float* T = tgt + (size_t)b * 3 * NPTS;
    const float R0 = Rt[b*16+0], R1 = Rt[b*16+1], R2 = Rt[b*16+2];
    const float R3 = Rt[b*16+3], R4 = Rt[b*16+4], R5 = Rt[b*16+5];
    const float R6 = Rt[b*16+6], R7 = Rt[b*16+7], R8 = Rt[b*16+8];
    const float t0 = Rt[b*16+9], t1 = Rt[b*16+10], t2 = Rt[b*16+11];

    __shared__ float4 stage4[NPTS];  // 64 KB
    const int nl = tid & 63;
    const int stripe = tid >> 6;
    const int n = blockIdx.x * 64 + nl;
    float4 p;

    if (z == 0) {
        for (int i = tid; i < NPTS; i += 1024) {
            float q0 = T[i], q1 = T[NPTS + i], q2 = T[2 * NPTS + i];
            float w = (q0 * q0 + q1 * q1 + q2 * q2) * -0.5f;
            stage4[i] = make_float4(q0, q1, q2, w);
        }
        float s0 = S[n], s1 = S[NPTS + n], s2 = S[2 * NPTS + n];
        float p0 = R0 * s0 + R1 * s1 + R2 * s2 + t0;
        float p1 = R3 * s0 + R4 * s1 + R5 * s2 + t1;
        float p2 = R6 * s0 + R7 * s1 + R8 * s2 + t2;
        p = make_float4(p0, p1, p2, p0 * p0 + p1 * p1 + p2 * p2);
    } else {
        for (int i = tid; i < NPTS; i += 1024) {
            float s0 = S[i], s1 = S[NPTS + i], s2 = S[2 * NPTS + i];
            float p0 = R0 * s0 + R1 * s1 + R2 * s2 + t0;
            float p1 = R3 * s0 + R4 * s1 + R5 * s2 + t1;
            float p2 = R6 * s0 + R7 * s1 + R8 * s2 + t2;
            float w = (p0 * p0 + p1 * p1 + p2 * p2) * -0.5f;
            stage4[i] = make_float4(p0, p1, p2, w);
        }
        float q0 = T[n], q1 = T[NPTS + n], q2 = T[2 * NPTS + n];
        p = make_float4(q0, q1, q2, q0 * q0 + q1 * q1 + q2 * q2);
    }
    __syncthreads();

    const int m0 = stripe << 8;
    float best = -3.4e38f;
    int bi = m0;
    #pragma unroll 8
    for (int m = m0; m < m0 + 256; ++m) {
        float4 q = stage4[m];
        float s = fmaf(p.x, q.x, fmaf(p.y, q.y, fmaf(p.z, q.z, q.w)));
        if (s > best) { best = s; bi = m; }
    }
    __syncthreads();

    float* combd = (float*)stage4;
    int* combi = (int*)(combd + 1024);
    combd[tid] = best;
    combi[tid] = bi;
    __syncthreads();
    if (stripe == 0) {
        for (int s2 = 1; s2 < 16; ++s2) {
            float d2 = combd[s2 * 64 + nl];
            int i2 = combi[s2 * 64 + nl];
            if (d2 > best) { best = d2; bi = i2; }  // ties: lower m wins
        }
        float d = fmaf(-2.0f, best, p.w);
        float* nn = z ? nnq : nnp;
        int* idx = z ? idxq : idxp;
        nn[b * NPTS + n] = sqrtf(fmaxf(d, 0.f) + EPSF);
        idx[b * NPTS + n] = bi;
    }
}

// ============================================================================
// KCr: redundant median (4-pass radix select) + weights. Grid (64, NB, 2)
// x 1024. Each block redundantly selects sorted[2047] (bitwise-exact via
// uint order == float order on positive floats), then writes weights for
// its 64 own points.
// ============================================================================
__global__ void kcr(const float* __restrict__ nnp, const float* __restrict__ nnq,
                    const int* __restrict__ idxp, const int* __restrict__ idxq,
                    const float* __restrict__ src_n, const float* __restrict__ tgt_n,
                    const float* __restrict__ Rt,
                    const float* __restrict__ g_q, const float* __restrict__ k_p,
                    const float* __restrict__ k_q, float* __restrict__ out) {
    const int x = blockIdx.x;
    const int b = blockIdx.y;
    const int z = blockIdx.z;
    const int tid = threadIdx.x;
    const int wid = tid >> 6;
    const int lane = tid & 63;
    const float* a = (z ? nnq : nnp) + b * NPTS;

    unsigned int v[4];
    #pragma unroll
    for (int j = 0; j < 4; ++j)
        v[j] = __float_as_uint(a[tid + j * 1024]);

    __shared__ int hist[16][256];
    __shared__ int tot[256];
    __shared__ int digit_s, base_s;

    const int shifts[4]   = {23, 15, 7, 0};
    const unsigned him[4] = {0x00000000u, 0x7F800000u, 0x7FFF8000u, 0x7FFFFF80u};
    const unsigned dm[4]  = {0xFFu, 0xFFu, 0xFFu, 0x7Fu};

    unsigned int prefix = 0u;
    int rank = 2047;

    for (int p = 0; p < 4; ++p) {
        const int sh = shifts[p];
        const unsigned himask = him[p];
        const unsigned dmask = dm[p];

        for (int k2 = lane; k2 < 256; k2 += 64) hist[wid][k2] = 0;
        __syncthreads();

        #pragma unroll
        for (int j = 0; j < 4; ++j) {
            if ((v[j] & himask) == prefix)
                atomicAdd(&hist[wid][(v[j] >> sh) & dmask], 1);
        }
        __syncthreads();

        if (tid < 256) {
            int t = 0;
            #pragma unroll
            for (int w = 0; w < 16; ++w) t += hist[w][tid];
            tot[tid] = t;
        }
        __syncthreads();

        if (wid == 0) {
            int c0 = tot[4 * lane + 0], c1 = tot[4 * lane + 1];
            int c2 = tot[4 * lane + 2], c3 = tot[4 * lane + 3];
            int s = c0 + c1 + c2 + c3;
            int incl = s;
            #pragma unroll
            for (int o = 1; o < 64; o <<= 1) {
                int t = __shfl_up(incl, o, 64);
                if (lane >= o) incl += t;
            }
            int base = incl - s;
            int cs[4] = {c0, c1, c2, c3};
            #pragma unroll
            for (int k2 = 0; k2 < 4; ++k2) {
                if (cs[k2] > 0 && rank >= base && rank < base + cs[k2]) {
                    digit_s = 4 * lane + k2;   // unique writer
                    base_s = base;
                }
                base += cs[k2];
            }
        }
        __syncthreads();
        prefix |= ((unsigned)digit_s) << sh;
        rank -= base_s;
        __syncthreads();
    }
    const float tauv = 3.0f * __uint_as_float(prefix);

    if (tid < 64) {
        const int n = x * 64 + tid;
        const float* SN = src_n + (size_t)b * 3 * NPTS;
        const float* TN = tgt_n + (size_t)b * 3 * NPTS;
        const float R0 = Rt[b*16+0], R1 = Rt[b*16+1], R2 = Rt[b*16+2];
        const float R3 = Rt[b*16+3], R4 = Rt[b*16+4], R5 = Rt[b*16+5];
        const float R6 = Rt[b*16+6], R7 = Rt[b*16+7], R8 = Rt[b*16+8];
        const float gx = g_q[3 * b + 0], gy = g_q[3 * b + 1], gz = g_q[3 * b + 2];
        const float kp = k_p[b], kq = k_q[b];
        const float keff = kp * kq / (kp + kq + EPSF);

        float w;
        if (z == 0) {
            float a0 = SN[n], a1 = SN[NPTS + n], a2 = SN[2 * NPTS + n];
            float snx = R0 * a0 + R1 * a1 + R2 * a2;
            float sny = R3 * a0 + R4 * a1 + R5 * a2;
            float snz = R6 * a0 + R7 * a1 + R8 * a2;
            float inc = snx * gx + sny * gy + snz * gz;
            int jj = idxp[b * NPTS + n];
            float tnx = TN[jj], tny = TN[NPTS + jj], tnz = TN[2 * NPTS + jj];
            float incr = tnx * gx + tny * gy + tnz * gz;
            float diff = inc - incr;
            float arg = 9.0f - keff * diff * diff;
            float sig = 1.f / (1.f + expf(-arg));
            float geom = (a[n] <= tauv) ? 1.f : 0.f;
            w = sig * geom;
        } else {
            float tnx = TN[n], tny = TN[NPTS + n], tnz = TN[2 * NPTS + n];
            float inc = tnx * gx + tny * gy + tnz * gz;
            int jj = idxq[b * NPTS + n];
            float a0 = SN[jj], a1 = SN[NPTS + jj], a2 = SN[2 * NPTS + jj];
            float snx = R0 * a0 + R1 * a1 + R2 * a2;
            float sny = R3 * a0 + R4 * a1 + R5 * a2;
            float snz = R6 * a0 + R7 * a1 + R8 * a2;
            float incr = snx * gx + sny * gy + snz * gz;
            float diff = inc - incr;
            float arg = 9.0f - keff * diff * diff;
            float sig = 1.f / (1.f + expf(-arg));
            float geom = (a[n] <= tauv) ? 1.f : 0.f;
            w = sig * geom;
        }
        out[z * (NB * NPTS) + b * NPTS + n] = w;
    }
}

extern "C" void kernel_launch(void* const* d_in, const int* in_sizes, int n_in,
                              void* d_out, int out_size, void* d_ws, size_t ws_size,
                              hipStream_t stream) {
    const float* src   = (const float*)d_in[0];
    const float* tgt   = (const float*)d_in[1];
    const float* src_n = (const float*)d_in[2];
    const float* tgt_n = (const float*)d_in[3];
    const float* g_p   = (const float*)d_in[4];
    const float* k_p   = (const float*)d_in[5];
    const float* g_q   = (const float*)d_in[6];
    const float* k_q   = (const float*)d_in[7];
    float* out = (float*)d_out;

    const int BN = NB * NPTS;
    float* nnp = (float*)d_ws;
    float* nnq = nnp + BN;
    int* idxp = (int*)(nnq + BN);
    int* idxq = idxp + BN;
    float* Rt  = (float*)(idxq + BN);   // NB*16 floats

    k0a_rt<<<dim3(NB), dim3(256), 0, stream>>>(src, tgt, g_p, g_q, Rt);
    k1r<<<dim3(NPTS / 64, NB, 2), dim3(1024), 0, stream>>>(src, tgt, Rt,
                                                           nnp, idxp, nnq, idxq);
    kcr<<<dim3(NPTS / 64, NB, 2), dim3(1024), 0, stream>>>(nnp, nnq, idxp, idxq,
                                                           src_n, tgt_n, Rt,
                                                           g_q, k_p, k_q, out);
}